// Round 1
// baseline (3053.658 us; speedup 1.0000x reference)
//
#include <hip/hip_runtime.h>
#include <math.h>

#define BB 32
#define LL 4096
#define DM 16
#define DI 32
#define DS 16
#define KC 4
#define NPOS (BB*LL)
#define TT 64
#define NTILE (LL/TT)

__device__ __forceinline__ float sigmoidf_(float x) { return 1.0f / (1.0f + __expf(-x)); }
__device__ __forceinline__ float siluf_(float x)    { return x * sigmoidf_(x); }
__device__ __forceinline__ float softplusf_(float x) {
    return fmaxf(x, 0.0f) + log1pf(__expf(-fabsf(x)));
}

// dot of 16 LDS floats (w) with 16 register floats (xn)
__device__ __forceinline__ float dot16(const float* w, const float* xn) {
    float acc = 0.0f;
#pragma unroll
    for (int m4 = 0; m4 < 4; ++m4) {
        float4 wv = *(const float4*)(w + m4 * 4);
        acc += wv.x * xn[m4*4+0] + wv.y * xn[m4*4+1] + wv.z * xn[m4*4+2] + wv.w * xn[m4*4+3];
    }
    return acc;
}

// ---------------- K0: h0 = x @ lin_in_w.T + b ----------------
__global__ __launch_bounds__(256) void k_lin_in(const float* __restrict__ x,
                                                const float* __restrict__ w,
                                                const float* __restrict__ bia,
                                                float* __restrict__ hin) {
    __shared__ float xs[16 * 64];
    __shared__ float s_w[16 * 68];   // rows padded 64->68 (bank-conflict break)
    __shared__ float bs[16];
    int tid = threadIdx.x;
    {   // 16x64 weights, one float4 per thread
        int r = tid >> 4, c4 = tid & 15;
        float4 v = ((const float4*)w)[r * 16 + c4];
        s_w[r*68 + c4*4+0] = v.x; s_w[r*68 + c4*4+1] = v.y;
        s_w[r*68 + c4*4+2] = v.z; s_w[r*68 + c4*4+3] = v.w;
    }
    if (tid < 16) bs[tid] = bia[tid];
    long base = (long)blockIdx.x * 16;              // 16 positions per block
    ((float4*)xs)[tid] = ((const float4*)x)[base * 16 + tid];
    __syncthreads();
    int pl = tid >> 4, j = tid & 15;
    float acc = bs[j];
#pragma unroll
    for (int k4 = 0; k4 < 16; ++k4) {
        float4 xv = *(const float4*)(xs + pl * 64 + k4 * 4);
        float4 wv = *(const float4*)(s_w + j * 68 + k4 * 4);
        acc += xv.x * wv.x + xv.y * wv.y + xv.z * wv.z + xv.w * wv.w;
    }
    hin[(base + pl) * 16 + j] = acc;
}

// ---------------- K1: all pre-scan work for one layer ----------------
// stores per pos: dxc[64] = {delta,xc} interleaved; bc[32] = {B,C} interleaved; z[32]
__global__ __launch_bounds__(256) void k_pre(const float* __restrict__ hin,
                                             const float* __restrict__ norm_w,
                                             const float* __restrict__ ipw,   // (64,16)
                                             const float* __restrict__ convw, // (32,4)
                                             const float* __restrict__ convb, // (32)
                                             const float* __restrict__ xpw,   // (33,32)
                                             const float* __restrict__ dtw,   // (32)
                                             const float* __restrict__ dtb,   // (32)
                                             float* __restrict__ dxc,
                                             float* __restrict__ bcb,
                                             float* __restrict__ zb) {
    __shared__ float s_norm[16];
    __shared__ float s_ipw[64 * 16];
    __shared__ float s_convw[32 * 4];
    __shared__ float s_convb[32];
    __shared__ float s_xpw[33 * 32];
    __shared__ float s_dtw[32];
    __shared__ float s_dtb[32];
    int tid = threadIdx.x;
    if (tid < 16) s_norm[tid] = norm_w[tid];
    for (int i = tid; i < 64 * 16; i += 256) s_ipw[i] = ipw[i];
    if (tid < 128) s_convw[tid] = convw[tid];
    if (tid < 32) s_convb[tid] = convb[tid];
    for (int i = tid; i < 33 * 32; i += 256) s_xpw[i] = xpw[i];
    if (tid < 32) { s_dtw[tid] = dtw[tid]; s_dtb[tid] = dtb[tid]; }
    __syncthreads();

    int pos = blockIdx.x * 256 + tid;
    int t = pos & (LL - 1);

    float xc[32], z[32];
    // tap k=0 (always valid): init conv accumulator and compute z
    {
        const float* hp = hin + (long)pos * 16;
        float hv[16];
        *(float4*)&hv[0]  = ((const float4*)hp)[0];
        *(float4*)&hv[4]  = ((const float4*)hp)[1];
        *(float4*)&hv[8]  = ((const float4*)hp)[2];
        *(float4*)&hv[12] = ((const float4*)hp)[3];
        float ssq = 0.0f;
#pragma unroll
        for (int m = 0; m < 16; ++m) ssq += hv[m] * hv[m];
        float sc = rsqrtf(ssq * (1.0f / 16.0f) + 1e-5f);
        float xn[16];
#pragma unroll
        for (int m = 0; m < 16; ++m) xn[m] = hv[m] * sc * s_norm[m];
#pragma unroll
        for (int c = 0; c < 32; ++c) {
            xc[c] = s_convw[c * 4 + 3] * dot16(&s_ipw[c * 16], xn);
            z[c]  = dot16(&s_ipw[(32 + c) * 16], xn);
        }
    }
    // taps k=1..3
    for (int k = 1; k < KC; ++k) {
        if (t - k < 0) break;
        const float* hp = hin + (long)(pos - k) * 16;
        float hv[16];
        *(float4*)&hv[0]  = ((const float4*)hp)[0];
        *(float4*)&hv[4]  = ((const float4*)hp)[1];
        *(float4*)&hv[8]  = ((const float4*)hp)[2];
        *(float4*)&hv[12] = ((const float4*)hp)[3];
        float ssq = 0.0f;
#pragma unroll
        for (int m = 0; m < 16; ++m) ssq += hv[m] * hv[m];
        float sc = rsqrtf(ssq * (1.0f / 16.0f) + 1e-5f);
        float xn[16];
#pragma unroll
        for (int m = 0; m < 16; ++m) xn[m] = hv[m] * sc * s_norm[m];
#pragma unroll
        for (int c = 0; c < 32; ++c)
            xc[c] += s_convw[c * 4 + (3 - k)] * dot16(&s_ipw[c * 16], xn);
    }
#pragma unroll
    for (int c = 0; c < 32; ++c) xc[c] = siluf_(xc[c] + s_convb[c]);

    float dbc[33];
#pragma unroll
    for (int r = 0; r < 33; ++r) {
        float acc = 0.0f;
#pragma unroll
        for (int c4 = 0; c4 < 8; ++c4) {
            float4 wv = *(const float4*)&s_xpw[r * 32 + c4 * 4];
            acc += wv.x * xc[c4*4+0] + wv.y * xc[c4*4+1] + wv.z * xc[c4*4+2] + wv.w * xc[c4*4+3];
        }
        dbc[r] = acc;
    }

    float* drow = dxc + (long)pos * 64;
#pragma unroll
    for (int i = 0; i < 16; ++i) {
        int e0 = 2 * i, e1 = 2 * i + 1;
        float d0 = softplusf_(dbc[0] * s_dtw[e0] + s_dtb[e0]);
        float d1 = softplusf_(dbc[0] * s_dtw[e1] + s_dtb[e1]);
        ((float4*)drow)[i] = make_float4(d0, xc[e0], d1, xc[e1]);
    }
    float* brow = bcb + (long)pos * 32;
#pragma unroll
    for (int i = 0; i < 8; ++i)
        ((float4*)brow)[i] = make_float4(dbc[1 + 2*i], dbc[17 + 2*i], dbc[2 + 2*i], dbc[18 + 2*i]);
    float* zrow = zb + (long)pos * 32;
#pragma unroll
    for (int i = 0; i < 8; ++i)
        ((float4*)zrow)[i] = make_float4(z[4*i], z[4*i+1], z[4*i+2], z[4*i+3]);
}

// ---------------- K2: sequential scan + epilogue (one block per batch) ----------------
template <bool FINAL>
__global__ __launch_bounds__(512) void k_scan(float* __restrict__ hin,   // in: residual base; out: layer output (non-final)
                                              const float* __restrict__ dxc,
                                              const float* __restrict__ bcb,
                                              const float* __restrict__ zb,
                                              const float* __restrict__ A_log, // (32,16)
                                              const float* __restrict__ Dp,    // (32)
                                              const float* __restrict__ opw,   // (16,32)
                                              const float* __restrict__ low,   // (16)
                                              const float* __restrict__ lob,   // (1)
                                              float* __restrict__ out) {
    __shared__ float s_dxc[2][TT * 64];
    __shared__ float s_bc [2][TT * 32];
    __shared__ float s_z  [2][TT * 32];
    __shared__ float s_hin[2][TT * 16];
    __shared__ float s_g  [TT * 36];     // padded stride
    __shared__ float s_opw[16 * 36];     // padded stride
    __shared__ float s_low[16];
    __shared__ float s_lob;

    int tid = threadIdx.x;
    int b = blockIdx.x;
    int e = tid >> 4, n = tid & 15;
    float a_en = -__expf(A_log[e * 16 + n]);
    float dDe = Dp[e];

    if (tid < 128) {
        float4 v = ((const float4*)opw)[tid];
        int r = tid >> 3, c = tid & 7;
        s_opw[r*36 + c*4+0] = v.x; s_opw[r*36 + c*4+1] = v.y;
        s_opw[r*36 + c*4+2] = v.z; s_opw[r*36 + c*4+3] = v.w;
    }
    if (tid < 16) s_low[tid] = low[tid];
    if (tid == 16) s_lob = lob[0];

    const float* gdxc = dxc + (long)b * LL * 64;
    const float* gbc  = bcb + (long)b * LL * 32;
    const float* gz   = zb  + (long)b * LL * 32;
    float* ghin = hin + (long)b * LL * 16;

    // tile 0 direct load
    ((float4*)s_dxc[0])[tid]       = ((const float4*)gdxc)[tid];
    ((float4*)s_dxc[0])[tid + 512] = ((const float4*)gdxc)[tid + 512];
    ((float4*)s_bc[0])[tid]        = ((const float4*)gbc)[tid];
    ((float4*)s_z[0])[tid]         = ((const float4*)gz)[tid];
    if (tid < 256) ((float4*)s_hin[0])[tid] = ((const float4*)ghin)[tid];
    __syncthreads();

    float h = 0.0f;
    for (int tile = 0; tile < NTILE; ++tile) {
        int cur = tile & 1, nxt = cur ^ 1;
        bool pf = (tile + 1 < NTILE);
        float4 p0, p1, p2, p3, p4;
        p4 = make_float4(0.f, 0.f, 0.f, 0.f);
        if (pf) {   // prefetch next tile into registers (loads fly during scan)
            long o = (long)(tile + 1) * TT;
            p0 = ((const float4*)(gdxc + o * 64))[tid];
            p1 = ((const float4*)(gdxc + o * 64))[tid + 512];
            p2 = ((const float4*)(gbc + o * 32))[tid];
            p3 = ((const float4*)(gz + o * 32))[tid];
            if (tid < 256) p4 = ((const float4*)(ghin + o * 16))[tid];
        }
        const float* cd = s_dxc[cur];
        const float* cb = s_bc[cur];
        const float* cz = s_z[cur];
#pragma unroll 4
        for (int tt = 0; tt < TT; ++tt) {
            float2 dx  = *(const float2*)&cd[tt * 64 + e * 2];  // {delta, xc}
            float2 bcv = *(const float2*)&cb[tt * 32 + n * 2];  // {B, C}
            float dA = __expf(dx.x * a_en);
            float bx = dx.x * dx.y * bcv.x;
            h = fmaf(dA, h, bx);
            float p = h * bcv.y;
            p += __shfl_xor(p, 1, 64);
            p += __shfl_xor(p, 2, 64);
            p += __shfl_xor(p, 4, 64);
            p += __shfl_xor(p, 8, 64);
            if (n == 0) {
                float y = fmaf(dDe, dx.y, p);
                float zz = cz[tt * 32 + e];
                s_g[tt * 36 + e] = y * (zz / (1.0f + __expf(-zz)));
            }
        }
        __syncthreads();
        // epilogue: out_proj + residual (+ fused lin_out on final layer)
        const float* ch = s_hin[cur];
#pragma unroll
        for (int it = 0; it < 2; ++it) {
            int idx = it * 512 + tid;
            int t = idx >> 4, j = idx & 15;
            float acc = 0.0f;
#pragma unroll
            for (int e4 = 0; e4 < 8; ++e4) {
                float4 wv = *(const float4*)&s_opw[j * 36 + e4 * 4];
                float4 gv = *(const float4*)&s_g[t * 36 + e4 * 4];
                acc += wv.x * gv.x + wv.y * gv.y + wv.z * gv.z + wv.w * gv.w;
            }
            float hv = ch[t * 16 + j] + acc;
            if (FINAL) {
                float part = s_low[j] * hv;
                part += __shfl_xor(part, 1, 64);
                part += __shfl_xor(part, 2, 64);
                part += __shfl_xor(part, 4, 64);
                part += __shfl_xor(part, 8, 64);
                if (j == 0) out[(long)b * LL + tile * TT + t] = part + s_lob;
            } else {
                ghin[(long)(tile * TT + t) * 16 + j] = hv;
            }
        }
        if (pf) {
            ((float4*)s_dxc[nxt])[tid]       = p0;
            ((float4*)s_dxc[nxt])[tid + 512] = p1;
            ((float4*)s_bc[nxt])[tid]        = p2;
            ((float4*)s_z[nxt])[tid]         = p3;
            if (tid < 256) ((float4*)s_hin[nxt])[tid] = p4;
        }
        __syncthreads();
    }
}

extern "C" void kernel_launch(void* const* d_in, const int* in_sizes, int n_in,
                              void* d_out, int out_size, void* d_ws, size_t ws_size,
                              hipStream_t stream) {
    const float* x   = (const float*)d_in[0];
    const float* liw = (const float*)d_in[1];
    const float* lib = (const float*)d_in[2];
    const float* low = (const float*)d_in[23];
    const float* lob = (const float*)d_in[24];

    // workspace partition (floats): hin 16/pos, dxc 64/pos, bc 32/pos, z 32/pos
    float* wf  = (float*)d_ws;
    float* hin = wf;
    float* dxc = hin + (size_t)NPOS * 16;
    float* bcb = dxc + (size_t)NPOS * 64;
    float* zb  = bcb + (size_t)NPOS * 32;

    float* outp = (float*)d_out;

    k_lin_in<<<NPOS / 16, 256, 0, stream>>>(x, liw, lib, hin);

    // layer 0
    {
        const float* nw  = (const float*)d_in[3];
        const float* ipw = (const float*)d_in[4];
        const float* cw  = (const float*)d_in[5];
        const float* cb  = (const float*)d_in[6];
        const float* xpw = (const float*)d_in[7];
        const float* dtw = (const float*)d_in[8];
        const float* dtb = (const float*)d_in[9];
        const float* alg = (const float*)d_in[10];
        const float* dp  = (const float*)d_in[11];
        const float* opw = (const float*)d_in[12];
        k_pre<<<NPOS / 256, 256, 0, stream>>>(hin, nw, ipw, cw, cb, xpw, dtw, dtb, dxc, bcb, zb);
        k_scan<false><<<BB, 512, 0, stream>>>(hin, dxc, bcb, zb, alg, dp, opw, low, lob, outp);
    }
    // layer 1 (lin_out fused into scan epilogue)
    {
        const float* nw  = (const float*)d_in[13];
        const float* ipw = (const float*)d_in[14];
        const float* cw  = (const float*)d_in[15];
        const float* cb  = (const float*)d_in[16];
        const float* xpw = (const float*)d_in[17];
        const float* dtw = (const float*)d_in[18];
        const float* dtb = (const float*)d_in[19];
        const float* alg = (const float*)d_in[20];
        const float* dp  = (const float*)d_in[21];
        const float* opw = (const float*)d_in[22];
        k_pre<<<NPOS / 256, 256, 0, stream>>>(hin, nw, ipw, cw, cb, xpw, dtw, dtb, dxc, bcb, zb);
        k_scan<true><<<BB, 512, 0, stream>>>(hin, dxc, bcb, zb, alg, dp, opw, low, lob, outp);
    }
}

// Round 2
// 569.503 us; speedup vs baseline: 5.3620x; 5.3620x over previous
//
#include <hip/hip_runtime.h>
#include <math.h>

#define BB 32
#define LL 4096
#define KC 4
#define NPOS (BB*LL)
#define NC 32           // chunks per sequence
#define CS 128          // chunk size (NC*CS == LL)
#define SUBA 64         // pass-A LDS sub-tile
#define SUBC 32         // pass-C LDS sub-tile
#define PT 256          // positions per k_pre block

__device__ __forceinline__ float sigmoidf_(float x) { return 1.0f / (1.0f + __expf(-x)); }
__device__ __forceinline__ float siluf_(float x)    { return x * sigmoidf_(x); }
__device__ __forceinline__ float softplusf_(float x) {
    return fmaxf(x, 0.0f) + log1pf(__expf(-fabsf(x)));
}

__device__ __forceinline__ float dot16(const float* w, const float* xn) {
    float acc = 0.0f;
#pragma unroll
    for (int m4 = 0; m4 < 4; ++m4) {
        float4 wv = *(const float4*)(w + m4 * 4);
        acc += wv.x * xn[m4*4+0] + wv.y * xn[m4*4+1] + wv.z * xn[m4*4+2] + wv.w * xn[m4*4+3];
    }
    return acc;
}

// ---------------- K0: h0 = x @ lin_in_w.T + b ----------------
__global__ __launch_bounds__(256) void k_lin_in(const float* __restrict__ x,
                                                const float* __restrict__ w,
                                                const float* __restrict__ bia,
                                                float* __restrict__ hin) {
    __shared__ float xs[16 * 64];
    __shared__ float s_w[16 * 68];
    __shared__ float bs[16];
    int tid = threadIdx.x;
    {
        int r = tid >> 4, c4 = tid & 15;
        float4 v = ((const float4*)w)[r * 16 + c4];
        s_w[r*68 + c4*4+0] = v.x; s_w[r*68 + c4*4+1] = v.y;
        s_w[r*68 + c4*4+2] = v.z; s_w[r*68 + c4*4+3] = v.w;
    }
    if (tid < 16) bs[tid] = bia[tid];
    long base = (long)blockIdx.x * 16;
    ((float4*)xs)[tid] = ((const float4*)x)[base * 16 + tid];
    __syncthreads();
    int pl = tid >> 4, j = tid & 15;
    float acc = bs[j];
#pragma unroll
    for (int k4 = 0; k4 < 16; ++k4) {
        float4 xv = *(const float4*)(xs + pl * 64 + k4 * 4);
        float4 wv = *(const float4*)(s_w + j * 68 + k4 * 4);
        acc += xv.x * wv.x + xv.y * wv.y + xv.z * wv.z + xv.w * wv.w;
    }
    hin[(base + pl) * 16 + j] = acc;
}

// ---------------- K1: pre-scan for one layer ----------------
// block = (b, tc): 256 consecutive positions of one batch. xin staged in LDS
// (in_proj computed ONCE per position, conv reads 4 taps from LDS).
// outputs per pos: dxp[64]={delta,delta*xc} interleaved; B[16]; C[16];
//                  sz[32]=silu(z); res2[16]=hin + opw@(D*xc*sz)  (resid+D folded)
__global__ __launch_bounds__(256) void k_pre(const float* __restrict__ hin,
                                             const float* __restrict__ norm_w,
                                             const float* __restrict__ ipw,   // (64,16)
                                             const float* __restrict__ convw, // (32,4)
                                             const float* __restrict__ convb, // (32)
                                             const float* __restrict__ xpw,   // (33,32)
                                             const float* __restrict__ dtw,   // (32)
                                             const float* __restrict__ dtb,   // (32)
                                             const float* __restrict__ Dp,    // (32)
                                             const float* __restrict__ opw,   // (16,32)
                                             float* __restrict__ dxp,
                                             float* __restrict__ Bb,
                                             float* __restrict__ Cb,
                                             float* __restrict__ szb,
                                             float* __restrict__ res2) {
    __shared__ float s_xin[(PT + 3) * 33];
    __shared__ float s_norm[16];
    __shared__ float s_ipw[64 * 16];
    __shared__ float s_convw[32 * 4];
    __shared__ float s_convb[32];
    __shared__ float s_xpw[33 * 32];
    __shared__ float s_dtw[32];
    __shared__ float s_dtb[32];
    __shared__ float s_Dp[32];
    __shared__ float s_opw[16 * 32];
    int tid = threadIdx.x;
    if (tid < 16) s_norm[tid] = norm_w[tid];
    for (int i = tid; i < 64 * 16; i += 256) s_ipw[i] = ipw[i];
    if (tid < 128) s_convw[tid] = convw[tid];
    if (tid < 32) s_convb[tid] = convb[tid];
    for (int i = tid; i < 33 * 32; i += 256) s_xpw[i] = xpw[i];
    if (tid < 32) { s_dtw[tid] = dtw[tid]; s_dtb[tid] = dtb[tid]; s_Dp[tid] = Dp[tid]; }
    for (int i = tid; i < 16 * 32; i += 256) s_opw[i] = opw[i];
    __syncthreads();

    int b = blockIdx.x >> 4, tc = blockIdx.x & 15;
    long pos0 = (long)b * LL + (long)tc * PT;

    // halo: 3 positions before the block (zero if before sequence start)
    if (tid < 3) {
        int tg = tc * PT - 3 + tid;
        if (tg < 0) {
            for (int c = 0; c < 32; ++c) s_xin[tid * 33 + c] = 0.0f;
        } else {
            const float* hp = hin + (pos0 - 3 + tid) * 16;
            float hv[16];
            *(float4*)&hv[0]  = ((const float4*)hp)[0];
            *(float4*)&hv[4]  = ((const float4*)hp)[1];
            *(float4*)&hv[8]  = ((const float4*)hp)[2];
            *(float4*)&hv[12] = ((const float4*)hp)[3];
            float ssq = 0.0f;
#pragma unroll
            for (int m = 0; m < 16; ++m) ssq += hv[m] * hv[m];
            float sc = rsqrtf(ssq * (1.0f / 16.0f) + 1e-5f);
            float xn[16];
#pragma unroll
            for (int m = 0; m < 16; ++m) xn[m] = hv[m] * sc * s_norm[m];
#pragma unroll
            for (int c = 0; c < 32; ++c) s_xin[tid * 33 + c] = dot16(&s_ipw[c * 16], xn);
        }
    }

    // main position
    long pos = pos0 + tid;
    float hv[16], z[32];
    {
        const float* hp = hin + pos * 16;
        *(float4*)&hv[0]  = ((const float4*)hp)[0];
        *(float4*)&hv[4]  = ((const float4*)hp)[1];
        *(float4*)&hv[8]  = ((const float4*)hp)[2];
        *(float4*)&hv[12] = ((const float4*)hp)[3];
        float ssq = 0.0f;
#pragma unroll
        for (int m = 0; m < 16; ++m) ssq += hv[m] * hv[m];
        float sc = rsqrtf(ssq * (1.0f / 16.0f) + 1e-5f);
        float xn[16];
#pragma unroll
        for (int m = 0; m < 16; ++m) xn[m] = hv[m] * sc * s_norm[m];
#pragma unroll
        for (int c = 0; c < 32; ++c) {
            s_xin[(tid + 3) * 33 + c] = dot16(&s_ipw[c * 16], xn);
            z[c] = dot16(&s_ipw[(32 + c) * 16], xn);
        }
    }
    __syncthreads();

    float xc[32];
#pragma unroll
    for (int c = 0; c < 32; ++c) {
        float acc = s_convb[c];
#pragma unroll
        for (int k = 0; k < KC; ++k)
            acc += s_convw[c * 4 + k] * s_xin[(tid + k) * 33 + c];
        xc[c] = siluf_(acc);
    }

    float dbc[33];
#pragma unroll
    for (int r = 0; r < 33; ++r) {
        float acc = 0.0f;
#pragma unroll
        for (int c4 = 0; c4 < 8; ++c4) {
            float4 wv = *(const float4*)&s_xpw[r * 32 + c4 * 4];
            acc += wv.x * xc[c4*4+0] + wv.y * xc[c4*4+1] + wv.z * xc[c4*4+2] + wv.w * xc[c4*4+3];
        }
        dbc[r] = acc;
    }

    // delta + dxp row {delta, delta*xc}
    float* drow = dxp + pos * 64;
#pragma unroll
    for (int i = 0; i < 16; ++i) {
        int e0 = 2 * i, e1 = 2 * i + 1;
        float d0 = softplusf_(dbc[0] * s_dtw[e0] + s_dtb[e0]);
        float d1 = softplusf_(dbc[0] * s_dtw[e1] + s_dtb[e1]);
        ((float4*)drow)[i] = make_float4(d0, d0 * xc[e0], d1, d1 * xc[e1]);
    }
    float* brow = Bb + pos * 16;
    float* crow = Cb + pos * 16;
#pragma unroll
    for (int i = 0; i < 4; ++i) {
        ((float4*)brow)[i] = make_float4(dbc[1 + 4*i], dbc[2 + 4*i], dbc[3 + 4*i], dbc[4 + 4*i]);
        ((float4*)crow)[i] = make_float4(dbc[17 + 4*i], dbc[18 + 4*i], dbc[19 + 4*i], dbc[20 + 4*i]);
    }
    float sz[32];
#pragma unroll
    for (int c = 0; c < 32; ++c) sz[c] = siluf_(z[c]);
    float* szrow = szb + pos * 32;
#pragma unroll
    for (int i = 0; i < 8; ++i)
        ((float4*)szrow)[i] = make_float4(sz[4*i], sz[4*i+1], sz[4*i+2], sz[4*i+3]);

    float tmp[32];
#pragma unroll
    for (int c = 0; c < 32; ++c) tmp[c] = s_Dp[c] * xc[c] * sz[c];
    float* rrow = res2 + pos * 16;
#pragma unroll
    for (int j4 = 0; j4 < 4; ++j4) {
        float4 o;
        float* po = (float*)&o;
#pragma unroll
        for (int jj = 0; jj < 4; ++jj) {
            int j = j4 * 4 + jj;
            float acc = hv[j];
#pragma unroll
            for (int e4 = 0; e4 < 8; ++e4) {
                float4 wv = *(const float4*)&s_opw[j * 32 + e4 * 4];
                acc += wv.x * tmp[e4*4+0] + wv.y * tmp[e4*4+1] + wv.z * tmp[e4*4+2] + wv.w * tmp[e4*4+3];
            }
            po[jj] = acc;
        }
        ((float4*)rrow)[j4] = o;
    }
}

// ---------------- K2a: chunk-local scan (h from 0) + dA product ----------------
__global__ __launch_bounds__(512) void k_scanA(const float* __restrict__ dxp,
                                               const float* __restrict__ Bb,
                                               const float* __restrict__ A_log,
                                               float* __restrict__ hl,
                                               float* __restrict__ Pp) {
    __shared__ float s_dxp[SUBA * 64];
    __shared__ float s_B[SUBA * 16];
    int tid = threadIdx.x;
    int bc = blockIdx.x, b = bc >> 5, c = bc & 31;
    int e = tid >> 4, n = tid & 15;
    float a_en = -__expf(A_log[tid]);   // A_log[e*16+n], tid == e*16+n

    const float* gd = dxp + ((long)b * LL + (long)c * CS) * 64;
    const float* gB = Bb  + ((long)b * LL + (long)c * CS) * 16;

    float h = 0.0f, P = 1.0f;
#pragma unroll
    for (int st = 0; st < CS / SUBA; ++st) {
        __syncthreads();
        ((float4*)s_dxp)[tid]       = ((const float4*)(gd + st * SUBA * 64))[tid];
        ((float4*)s_dxp)[tid + 512] = ((const float4*)(gd + st * SUBA * 64))[tid + 512];
        if (tid < 256) ((float4*)s_B)[tid] = ((const float4*)(gB + st * SUBA * 16))[tid];
        __syncthreads();
#pragma unroll 8
        for (int tt = 0; tt < SUBA; ++tt) {
            float2 dx = *(const float2*)&s_dxp[tt * 64 + (e << 1)];
            float dA = __expf(dx.x * a_en);
            h = fmaf(dA, h, dx.y * s_B[tt * 16 + n]);
            P *= dA;
        }
    }
    int o = bc * 512 + tid;
    hl[o] = h;
    Pp[o] = P;
}

// ---------------- K2b: combine chunk summaries -> h_init per chunk ----------------
__global__ __launch_bounds__(512) void k_comb(const float* __restrict__ hl,
                                              const float* __restrict__ Pp,
                                              float* __restrict__ hinit) {
    int b = blockIdx.x, tid = threadIdx.x;
    float Pv[NC], Hv[NC];
#pragma unroll
    for (int c = 0; c < NC; ++c) {
        int o = (b * NC + c) * 512 + tid;
        Pv[c] = Pp[o];
        Hv[c] = hl[o];
    }
    float x = 0.0f;
#pragma unroll
    for (int c = 0; c < NC; ++c) {
        hinit[(b * NC + c) * 512 + tid] = x;
        x = fmaf(Pv[c], x, Hv[c]);
    }
}

// ---------------- K2c: re-scan with h_init, y + fused epilogue ----------------
template <bool FINAL>
__global__ __launch_bounds__(512) void k_scanC(const float* __restrict__ dxp,
                                               const float* __restrict__ Bb,
                                               const float* __restrict__ Cb,
                                               const float* __restrict__ szb,
                                               const float* __restrict__ res2,
                                               const float* __restrict__ hinit,
                                               const float* __restrict__ A_log,
                                               const float* __restrict__ opw,   // (16,32)
                                               const float* __restrict__ low,   // (16)
                                               const float* __restrict__ lob,   // (1)
                                               float* __restrict__ hout,        // next-layer hin (non-final)
                                               float* __restrict__ out) {       // final output
    __shared__ float s_dxp[SUBC * 64];
    __shared__ float s_B[SUBC * 16];
    __shared__ float s_C[SUBC * 16];
    __shared__ float s_sz[SUBC * 32];
    __shared__ float s_g[SUBC * 36];
    __shared__ float s_opw[16 * 36];
    __shared__ float s_low[16];
    __shared__ float s_lob;

    int tid = threadIdx.x;
    int bc = blockIdx.x, b = bc >> 5, c = bc & 31;
    int e = tid >> 4, n = tid & 15;
    float a_en = -__expf(A_log[tid]);

    if (tid < 128) {
        float4 v = ((const float4*)opw)[tid];
        int r = tid >> 3, cc = tid & 7;
        s_opw[r*36 + cc*4+0] = v.x; s_opw[r*36 + cc*4+1] = v.y;
        s_opw[r*36 + cc*4+2] = v.z; s_opw[r*36 + cc*4+3] = v.w;
    }
    if (FINAL) {
        if (tid < 16) s_low[tid] = low[tid];
        if (tid == 16) s_lob = lob[0];
    }

    long cbase = (long)b * LL + (long)c * CS;
    const float* gd  = dxp + cbase * 64;
    const float* gB  = Bb  + cbase * 16;
    const float* gC  = Cb  + cbase * 16;
    const float* gsz = szb + cbase * 32;

    float h = hinit[bc * 512 + tid];

#pragma unroll
    for (int st = 0; st < CS / SUBC; ++st) {
        __syncthreads();
        // stage: dxp 2048 floats (512 f4), B 512 (128 f4), C 512, sz 1024 (256 f4)
        ((float4*)s_dxp)[tid] = ((const float4*)(gd + st * SUBC * 64))[tid];
        if (tid < 128)      ((float4*)s_B)[tid]        = ((const float4*)(gB + st * SUBC * 16))[tid];
        else if (tid < 256) ((float4*)s_C)[tid - 128]  = ((const float4*)(gC + st * SUBC * 16))[tid - 128];
        else                ((float4*)s_sz)[tid - 256] = ((const float4*)(gsz + st * SUBC * 32))[tid - 256];
        __syncthreads();
#pragma unroll 8
        for (int tt = 0; tt < SUBC; ++tt) {
            float2 dx = *(const float2*)&s_dxp[tt * 64 + (e << 1)];
            float dA = __expf(dx.x * a_en);
            h = fmaf(dA, h, dx.y * s_B[tt * 16 + n]);
            float p = h * s_C[tt * 16 + n];
            p += __shfl_xor(p, 1, 64);
            p += __shfl_xor(p, 2, 64);
            p += __shfl_xor(p, 4, 64);
            p += __shfl_xor(p, 8, 64);
            if (n == 0) s_g[tt * 36 + e] = p * s_sz[tt * 32 + e];
        }
        __syncthreads();
        // epilogue: 32 t x 16 j
        {
            int t = tid >> 4, j = tid & 15;
            long pos = cbase + st * SUBC + t;
            float acc = 0.0f;
#pragma unroll
            for (int e4 = 0; e4 < 8; ++e4) {
                float4 wv = *(const float4*)&s_opw[j * 36 + e4 * 4];
                float4 gv = *(const float4*)&s_g[t * 36 + e4 * 4];
                acc += wv.x * gv.x + wv.y * gv.y + wv.z * gv.z + wv.w * gv.w;
            }
            float val = res2[pos * 16 + j] + acc;
            if (FINAL) {
                float part = s_low[j] * val;
                part += __shfl_xor(part, 1, 64);
                part += __shfl_xor(part, 2, 64);
                part += __shfl_xor(part, 4, 64);
                part += __shfl_xor(part, 8, 64);
                if (j == 0) out[pos] = part + s_lob;
            } else {
                hout[pos * 16 + j] = val;
            }
        }
    }
}

extern "C" void kernel_launch(void* const* d_in, const int* in_sizes, int n_in,
                              void* d_out, int out_size, void* d_ws, size_t ws_size,
                              hipStream_t stream) {
    const float* x   = (const float*)d_in[0];
    const float* liw = (const float*)d_in[1];
    const float* lib = (const float*)d_in[2];
    const float* low = (const float*)d_in[23];
    const float* lob = (const float*)d_in[24];

    // workspace (floats): hin 16, dxp 64, B 16, C 16, sz 32, res2 16 per pos
    //                     + 3 x 512*NC*BB summaries  (~90 MB total)
    float* wf    = (float*)d_ws;
    float* hin   = wf;
    float* dxp   = hin  + (size_t)NPOS * 16;
    float* Bb    = dxp  + (size_t)NPOS * 64;
    float* Cb    = Bb   + (size_t)NPOS * 16;
    float* szb   = Cb   + (size_t)NPOS * 16;
    float* res2  = szb  + (size_t)NPOS * 32;
    float* hl    = res2 + (size_t)NPOS * 16;
    float* Pp    = hl   + (size_t)BB * NC * 512;
    float* hinit = Pp   + (size_t)BB * NC * 512;

    float* outp = (float*)d_out;

    k_lin_in<<<NPOS / 16, 256, 0, stream>>>(x, liw, lib, hin);

    for (int layer = 0; layer < 2; ++layer) {
        int o = 3 + layer * 10;
        const float* nw  = (const float*)d_in[o + 0];
        const float* ipw = (const float*)d_in[o + 1];
        const float* cw  = (const float*)d_in[o + 2];
        const float* cb  = (const float*)d_in[o + 3];
        const float* xpw = (const float*)d_in[o + 4];
        const float* dtw = (const float*)d_in[o + 5];
        const float* dtb = (const float*)d_in[o + 6];
        const float* alg = (const float*)d_in[o + 7];
        const float* dp  = (const float*)d_in[o + 8];
        const float* opw = (const float*)d_in[o + 9];

        k_pre<<<BB * (LL / PT), 256, 0, stream>>>(hin, nw, ipw, cw, cb, xpw, dtw, dtb,
                                                  dp, opw, dxp, Bb, Cb, szb, res2);
        k_scanA<<<BB * NC, 512, 0, stream>>>(dxp, Bb, alg, hl, Pp);
        k_comb<<<BB, 512, 0, stream>>>(hl, Pp, hinit);
        if (layer == 0) {
            k_scanC<false><<<BB * NC, 512, 0, stream>>>(dxp, Bb, Cb, szb, res2, hinit,
                                                        alg, opw, low, lob, hin, outp);
        } else {
            k_scanC<true><<<BB * NC, 512, 0, stream>>>(dxp, Bb, Cb, szb, res2, hinit,
                                                       alg, opw, low, lob, hin, outp);
        }
    }
}

// Round 3
// 437.718 us; speedup vs baseline: 6.9763x; 1.3011x over previous
//
#include <hip/hip_runtime.h>
#include <math.h>

#define BB 32
#define LL 4096
#define KC 4
#define NPOS (BB*LL)
#define NC 32           // chunks per sequence
#define CS 128          // chunk size (NC*CS == LL)
#define TA 64           // pass-A LDS sub-tile (t)
#define TC 32           // pass-C LDS sub-tile (t)
#define SA 68           // pass-A LDS row stride (floats, 16B-aligned, conflict-free)
#define SC 36           // pass-C LDS row stride
#define PT 256          // positions per k_pre block

__device__ __forceinline__ float sigmoidf_(float x) { return 1.0f / (1.0f + __expf(-x)); }
__device__ __forceinline__ float siluf_(float x)    { return x * sigmoidf_(x); }
__device__ __forceinline__ float softplusf_(float x) {
    return fmaxf(x, 0.0f) + log1pf(__expf(-fabsf(x)));
}

__device__ __forceinline__ float dot16(const float* w, const float* xn) {
    float acc = 0.0f;
#pragma unroll
    for (int m4 = 0; m4 < 4; ++m4) {
        float4 wv = *(const float4*)(w + m4 * 4);
        acc += wv.x * xn[m4*4+0] + wv.y * xn[m4*4+1] + wv.z * xn[m4*4+2] + wv.w * xn[m4*4+3];
    }
    return acc;
}

// ---------------- K0: hin[b][j][t] = x @ lin_in_w.T + b ----------------
__global__ __launch_bounds__(256) void k_lin_in(const float* __restrict__ x,
                                                const float* __restrict__ w,
                                                const float* __restrict__ bia,
                                                float* __restrict__ hin) {
    __shared__ float xs[16 * 68];
    __shared__ float s_w[16 * 68];
    __shared__ float bs[16];
    int tid = threadIdx.x;
    {
        int r = tid >> 4, c4 = tid & 15;
        float4 v = ((const float4*)w)[r * 16 + c4];
        *(float4*)&s_w[r * 68 + c4 * 4] = v;
    }
    if (tid < 16) bs[tid] = bia[tid];
    long base = (long)blockIdx.x * 16;          // 16 positions per block
    {
        int r = tid >> 4, c4 = tid & 15;
        float4 v = ((const float4*)x)[base * 16 + tid];
        *(float4*)&xs[r * 68 + c4 * 4] = v;
    }
    __syncthreads();
    int j = tid >> 4, pl = tid & 15;            // lanes: pl fastest -> coalesced t writes
    float acc = bs[j];
#pragma unroll
    for (int k4 = 0; k4 < 16; ++k4) {
        float4 xv = *(const float4*)(xs + pl * 68 + k4 * 4);
        float4 wv = *(const float4*)(s_w + j * 68 + k4 * 4);
        acc += xv.x * wv.x + xv.y * wv.y + xv.z * wv.z + xv.w * wv.w;
    }
    long pos = base + pl;
    int b = (int)(pos >> 12), t = (int)(pos & (LL - 1));
    hin[((long)b * 16 + j) * LL + t] = acc;
}

// ---------------- K1: pre-scan for one layer (all outputs feature-major [b][f][t]) ----
__global__ __launch_bounds__(256) void k_pre(const float* __restrict__ hin,
                                             const float* __restrict__ norm_w,
                                             const float* __restrict__ ipw,   // (64,16)
                                             const float* __restrict__ convw, // (32,4)
                                             const float* __restrict__ convb, // (32)
                                             const float* __restrict__ xpw,   // (33,32)
                                             const float* __restrict__ dtw,   // (32)
                                             const float* __restrict__ dtb,   // (32)
                                             const float* __restrict__ Dp,    // (32)
                                             const float* __restrict__ opw,   // (16,32)
                                             float* __restrict__ Da,    // [b][e][t] delta
                                             float* __restrict__ Xd,    // [b][e][t] delta*xc
                                             float* __restrict__ Bf,    // [b][n][t]
                                             float* __restrict__ Cf,    // [b][n][t]
                                             float* __restrict__ Sz,    // [b][e][t] silu(z)
                                             float* __restrict__ R2) {  // [b][j][t] resid+D-term
    __shared__ float s_xin[(PT + 3) * 33];
    __shared__ float s_norm[16];
    __shared__ float s_ipw[64 * 16];
    __shared__ float s_convw[32 * 4];
    __shared__ float s_convb[32];
    __shared__ float s_xpw[33 * 32];
    __shared__ float s_dtw[32];
    __shared__ float s_dtb[32];
    __shared__ float s_Dp[32];
    __shared__ float s_opw[16 * 32];
    int tid = threadIdx.x;
    if (tid < 16) s_norm[tid] = norm_w[tid];
    for (int i = tid; i < 64 * 16; i += 256) s_ipw[i] = ipw[i];
    if (tid < 128) s_convw[tid] = convw[tid];
    if (tid < 32) s_convb[tid] = convb[tid];
    for (int i = tid; i < 33 * 32; i += 256) s_xpw[i] = xpw[i];
    if (tid < 32) { s_dtw[tid] = dtw[tid]; s_dtb[tid] = dtb[tid]; s_Dp[tid] = Dp[tid]; }
    for (int i = tid; i < 16 * 32; i += 256) s_opw[i] = opw[i];
    __syncthreads();

    int b = blockIdx.x >> 4, tc = blockIdx.x & 15;
    int t = tc * PT + tid;                       // position within batch row
    const float* hb = hin + (long)b * 16 * LL;   // feature-major base

    // halo: 3 positions before the tile
    if (tid < 3) {
        int th = tc * PT - 3 + tid;
        if (th < 0) {
            for (int c = 0; c < 32; ++c) s_xin[tid * 33 + c] = 0.0f;
        } else {
            float hv[16];
#pragma unroll
            for (int j = 0; j < 16; ++j) hv[j] = hb[j * LL + th];
            float ssq = 0.0f;
#pragma unroll
            for (int m = 0; m < 16; ++m) ssq += hv[m] * hv[m];
            float sc = rsqrtf(ssq * (1.0f / 16.0f) + 1e-5f);
            float xn[16];
#pragma unroll
            for (int m = 0; m < 16; ++m) xn[m] = hv[m] * sc * s_norm[m];
#pragma unroll
            for (int c = 0; c < 32; ++c) s_xin[tid * 33 + c] = dot16(&s_ipw[c * 16], xn);
        }
    }

    // main position: 16 coalesced scalar loads, rmsnorm, in_proj (once)
    float hv[16], z[32];
    {
#pragma unroll
        for (int j = 0; j < 16; ++j) hv[j] = hb[j * LL + t];
        float ssq = 0.0f;
#pragma unroll
        for (int m = 0; m < 16; ++m) ssq += hv[m] * hv[m];
        float sc = rsqrtf(ssq * (1.0f / 16.0f) + 1e-5f);
        float xn[16];
#pragma unroll
        for (int m = 0; m < 16; ++m) xn[m] = hv[m] * sc * s_norm[m];
#pragma unroll
        for (int c = 0; c < 32; ++c) {
            s_xin[(tid + 3) * 33 + c] = dot16(&s_ipw[c * 16], xn);
            z[c] = dot16(&s_ipw[(32 + c) * 16], xn);
        }
    }
    __syncthreads();

    float xc[32];
#pragma unroll
    for (int c = 0; c < 32; ++c) {
        float acc = s_convb[c];
#pragma unroll
        for (int k = 0; k < KC; ++k)
            acc += s_convw[c * 4 + k] * s_xin[(tid + k) * 33 + c];
        xc[c] = siluf_(acc);
    }

    float dbc[33];
#pragma unroll
    for (int r = 0; r < 33; ++r) {
        float acc = 0.0f;
#pragma unroll
        for (int c4 = 0; c4 < 8; ++c4) {
            float4 wv = *(const float4*)&s_xpw[r * 32 + c4 * 4];
            acc += wv.x * xc[c4*4+0] + wv.y * xc[c4*4+1] + wv.z * xc[c4*4+2] + wv.w * xc[c4*4+3];
        }
        dbc[r] = acc;
    }

    long b32t = (long)b * 32 * LL + t;
    long b16t = (long)b * 16 * LL + t;

    float sz[32];
#pragma unroll
    for (int c = 0; c < 32; ++c) sz[c] = siluf_(z[c]);

    // coalesced scalar stores (consecutive lanes -> consecutive t)
#pragma unroll
    for (int e = 0; e < 32; ++e) {
        float d = softplusf_(dbc[0] * s_dtw[e] + s_dtb[e]);
        Da[b32t + (long)e * LL] = d;
        Xd[b32t + (long)e * LL] = d * xc[e];
    }
#pragma unroll
    for (int n = 0; n < 16; ++n) {
        Bf[b16t + (long)n * LL] = dbc[1 + n];
        Cf[b16t + (long)n * LL] = dbc[17 + n];
    }
#pragma unroll
    for (int e = 0; e < 32; ++e) Sz[b32t + (long)e * LL] = sz[e];

    float tmp[32];
#pragma unroll
    for (int c = 0; c < 32; ++c) tmp[c] = s_Dp[c] * xc[c] * sz[c];
#pragma unroll
    for (int j = 0; j < 16; ++j) {
        float acc = hv[j];
#pragma unroll
        for (int e4 = 0; e4 < 8; ++e4) {
            float4 wv = *(const float4*)&s_opw[j * 32 + e4 * 4];
            acc += wv.x * tmp[e4*4+0] + wv.y * tmp[e4*4+1] + wv.z * tmp[e4*4+2] + wv.w * tmp[e4*4+3];
        }
        R2[b16t + (long)j * LL] = acc;
    }
}

// ---------------- K2a: chunk-local scan (h from 0) + dA product ----------------
__global__ __launch_bounds__(512) void k_scanA(const float* __restrict__ Da,
                                               const float* __restrict__ Xd,
                                               const float* __restrict__ Bf,
                                               const float* __restrict__ A_log,
                                               float* __restrict__ hl,
                                               float* __restrict__ Pp) {
    __shared__ float s_da[32 * SA];
    __shared__ float s_xd[32 * SA];
    __shared__ float s_b[16 * SA];
    int tid = threadIdx.x;
    int bc = blockIdx.x, b = bc >> 5, c = bc & 31;
    int e = tid >> 4, n = tid & 15;
    float a_en = -__expf(A_log[tid]);

    const float* gDa = Da + (long)b * 32 * LL + c * CS;
    const float* gXd = Xd + (long)b * 32 * LL + c * CS;
    const float* gB  = Bf + (long)b * 16 * LL + c * CS;

    float h = 0.0f, P = 1.0f;
#pragma unroll
    for (int st = 0; st < CS / TA; ++st) {
        __syncthreads();
        int r = tid >> 4, t4 = (tid & 15) * 4, off = st * TA;
        *(float4*)&s_da[r * SA + t4] = *(const float4*)(gDa + (long)r * LL + off + t4);
        *(float4*)&s_xd[r * SA + t4] = *(const float4*)(gXd + (long)r * LL + off + t4);
        if (r < 16) *(float4*)&s_b[r * SA + t4] = *(const float4*)(gB + (long)r * LL + off + t4);
        __syncthreads();
#pragma unroll 16
        for (int tt = 0; tt < TA; ++tt) {
            float dA = __expf(s_da[e * SA + tt] * a_en);
            h = fmaf(dA, h, s_xd[e * SA + tt] * s_b[n * SA + tt]);
            P *= dA;
        }
    }
    int o = bc * 512 + tid;
    hl[o] = h;
    Pp[o] = P;
}

// ---------------- K2c: prefix-combine + re-scan + fused epilogue ----------------
template <bool FINAL>
__global__ __launch_bounds__(512) void k_scanC(const float* __restrict__ Da,
                                               const float* __restrict__ Xd,
                                               const float* __restrict__ Bf,
                                               const float* __restrict__ Cf,
                                               const float* __restrict__ Sz,
                                               const float* __restrict__ R2,
                                               const float* __restrict__ hl,
                                               const float* __restrict__ Pp,
                                               const float* __restrict__ A_log,
                                               const float* __restrict__ opw,   // (16,32)
                                               const float* __restrict__ low,   // (16)
                                               const float* __restrict__ lob,   // (1)
                                               float* __restrict__ hout,        // next hin [b][j][t]
                                               float* __restrict__ out) {
    __shared__ float s_da[32 * SC];
    __shared__ float s_xd[32 * SC];
    __shared__ float s_b[16 * SC];
    __shared__ float s_c[16 * SC];
    __shared__ float s_sz[32 * SC];
    __shared__ float s_g[TC * 36];
    __shared__ float s_opw[16 * 32];
    __shared__ float s_red[16 * 33];
    __shared__ float s_low[16];
    __shared__ float s_lob;

    int tid = threadIdx.x;
    int bc = blockIdx.x, b = bc >> 5, c = bc & 31;
    int e = tid >> 4, n = tid & 15;
    float a_en = -__expf(A_log[tid]);

    if (tid < 128) ((float4*)s_opw)[tid] = ((const float4*)opw)[tid];
    if (FINAL) {
        if (tid < 16) s_low[tid] = low[tid];
        if (tid == 16) s_lob = lob[0];
    }

    const float* gDa = Da + (long)b * 32 * LL + c * CS;
    const float* gXd = Xd + (long)b * 32 * LL + c * CS;
    const float* gB  = Bf + (long)b * 16 * LL + c * CS;
    const float* gC  = Cf + (long)b * 16 * LL + c * CS;
    const float* gSz = Sz + (long)b * 32 * LL + c * CS;

    // inline prefix combine (replaces k_comb): h_init from chunk summaries
    float h = 0.0f;
    for (int cp = 0; cp < c; ++cp) {
        int o = (b * NC + cp) * 512 + tid;
        h = fmaf(Pp[o], h, hl[o]);
    }

#pragma unroll
    for (int st = 0; st < CS / TC; ++st) {
        __syncthreads();
        {
            int rr = tid >> 3, t4 = (tid & 7) * 4, off = st * TC;
            // set 1: da / xd (64 rows)
            if (rr < 32) *(float4*)&s_da[rr * SC + t4] = *(const float4*)(gDa + (long)rr * LL + off + t4);
            else         *(float4*)&s_xd[(rr - 32) * SC + t4] = *(const float4*)(gXd + (long)(rr - 32) * LL + off + t4);
            // set 2: b / c / sz (64 rows)
            if (rr < 16)      *(float4*)&s_b[rr * SC + t4]        = *(const float4*)(gB + (long)rr * LL + off + t4);
            else if (rr < 32) *(float4*)&s_c[(rr - 16) * SC + t4] = *(const float4*)(gC + (long)(rr - 16) * LL + off + t4);
            else              *(float4*)&s_sz[(rr - 32) * SC + t4] = *(const float4*)(gSz + (long)(rr - 32) * LL + off + t4);
        }
        __syncthreads();
#pragma unroll 8
        for (int tt = 0; tt < TC; ++tt) {
            float dA = __expf(s_da[e * SC + tt] * a_en);
            h = fmaf(dA, h, s_xd[e * SC + tt] * s_b[n * SC + tt]);
            float p = h * s_c[n * SC + tt];
            p += __shfl_xor(p, 1, 64);
            p += __shfl_xor(p, 2, 64);
            p += __shfl_xor(p, 4, 64);
            p += __shfl_xor(p, 8, 64);
            if (n == 0) s_g[tt * 36 + e] = p * s_sz[e * SC + tt];
        }
        __syncthreads();
        // epilogue: j = tid>>5 (0..15), t = tid&31 -> coalesced global access
        {
            int j = tid >> 5, t = tid & 31;
            int tpos = c * CS + st * TC + t;
            float acc = 0.0f;
#pragma unroll
            for (int e4 = 0; e4 < 8; ++e4) {
                float4 wv = *(const float4*)&s_opw[j * 32 + e4 * 4];
                float4 gv = *(const float4*)&s_g[t * 36 + e4 * 4];
                acc += wv.x * gv.x + wv.y * gv.y + wv.z * gv.z + wv.w * gv.w;
            }
            float val = R2[((long)b * 16 + j) * LL + tpos] + acc;
            if (FINAL) {
                s_red[j * 33 + t] = s_low[j] * val;
                __syncthreads();
                if (tid < 32) {
                    float accj = s_lob;
#pragma unroll
                    for (int jj = 0; jj < 16; ++jj) accj += s_red[jj * 33 + tid];
                    out[(long)b * LL + c * CS + st * TC + tid] = accj;
                }
            } else {
                hout[((long)b * 16 + j) * LL + tpos] = val;
            }
        }
    }
}

extern "C" void kernel_launch(void* const* d_in, const int* in_sizes, int n_in,
                              void* d_out, int out_size, void* d_ws, size_t ws_size,
                              hipStream_t stream) {
    const float* x   = (const float*)d_in[0];
    const float* liw = (const float*)d_in[1];
    const float* lib = (const float*)d_in[2];
    const float* low = (const float*)d_in[23];
    const float* lob = (const float*)d_in[24];

    // workspace (floats), all feature-major [b][f][LL]
    float* wf  = (float*)d_ws;
    float* hin = wf;
    float* Da  = hin + (size_t)NPOS * 16;
    float* Xd  = Da  + (size_t)NPOS * 32;
    float* Bf  = Xd  + (size_t)NPOS * 32;
    float* Cf  = Bf  + (size_t)NPOS * 16;
    float* Sz  = Cf  + (size_t)NPOS * 16;
    float* R2  = Sz  + (size_t)NPOS * 32;
    float* hl  = R2  + (size_t)NPOS * 16;
    float* Pp  = hl  + (size_t)BB * NC * 512;

    float* outp = (float*)d_out;

    k_lin_in<<<NPOS / 16, 256, 0, stream>>>(x, liw, lib, hin);

    for (int layer = 0; layer < 2; ++layer) {
        int o = 3 + layer * 10;
        const float* nw  = (const float*)d_in[o + 0];
        const float* ipw = (const float*)d_in[o + 1];
        const float* cw  = (const float*)d_in[o + 2];
        const float* cb  = (const float*)d_in[o + 3];
        const float* xpw = (const float*)d_in[o + 4];
        const float* dtw = (const float*)d_in[o + 5];
        const float* dtb = (const float*)d_in[o + 6];
        const float* alg = (const float*)d_in[o + 7];
        const float* dp  = (const float*)d_in[o + 8];
        const float* opw = (const float*)d_in[o + 9];

        k_pre<<<BB * (LL / PT), 256, 0, stream>>>(hin, nw, ipw, cw, cb, xpw, dtw, dtb,
                                                  dp, opw, Da, Xd, Bf, Cf, Sz, R2);
        k_scanA<<<BB * NC, 512, 0, stream>>>(Da, Xd, Bf, alg, hl, Pp);
        if (layer == 0) {
            k_scanC<false><<<BB * NC, 512, 0, stream>>>(Da, Xd, Bf, Cf, Sz, R2, hl, Pp,
                                                        alg, opw, low, lob, hin, outp);
        } else {
            k_scanC<true><<<BB * NC, 512, 0, stream>>>(Da, Xd, Bf, Cf, Sz, R2, hl, Pp,
                                                       alg, opw, low, lob, hin, outp);
        }
    }
}